// Round 1
// baseline (75.113 us; speedup 1.0000x reference)
//
#include <hip/hip_runtime.h>
#include <hip/hip_bf16.h>

typedef __attribute__((ext_vector_type(8))) short bf16x8;
typedef __attribute__((ext_vector_type(4))) float f32x4;

__device__ __forceinline__ unsigned short f2bf(float f) {
    union { float f; unsigned int u; } v; v.f = f;
    unsigned int u = v.u;
    unsigned int r = u + 0x7FFFu + ((u >> 16) & 1u);   // RNE
    return (unsigned short)(r >> 16);
}

// ---------------- kernel 0: W transpose+convert -> Wt[192][384] bf16 ----------------
__global__ __launch_bounds__(256) void wprep(const float* __restrict__ Wq,
                                             const float* __restrict__ Wk,
                                             const float* __restrict__ Wv,
                                             unsigned short* __restrict__ Wt) {
    int idx = blockIdx.x * 256 + threadIdx.x;          // 3*64*384 = 73728
    if (idx >= 3 * 64 * 384) return;
    int w   = idx / (64 * 384);
    int rem = idx % (64 * 384);
    int n = rem / 384, k = rem % 384;
    const float* W = (w == 0) ? Wq : ((w == 1) ? Wk : Wv);
    Wt[idx] = f2bf(W[k * 64 + n]);
}

// ---------------- kernel 1: qkv = x @ [Wq|Wk|Wv], bf16 MFMA ----------------
// M=65536, K=384, N=192. Block tile 128x192, 4 waves (2x2), wave tile 64x96.
__global__ __launch_bounds__(256) void qkv_gemm(const float* __restrict__ x,
                                                const unsigned short* __restrict__ Wt,
                                                unsigned short* __restrict__ q_ws,
                                                unsigned short* __restrict__ k_ws,
                                                unsigned short* __restrict__ vt_ws) {
    __shared__ unsigned short A_lds[128 * 40];   // 128 rows x 32 k, pad to 40
    __shared__ unsigned short B_lds[192 * 40];   // 192 cols x 32 k, pad to 40

    const int tid  = threadIdx.x;
    const int lane = tid & 63;
    const int wid  = tid >> 6;
    const int wr = wid >> 1, wc = wid & 1;
    const int row0 = blockIdx.x * 128;
    const int l15 = lane & 15, lg = lane >> 4;

    f32x4 acc[4][6] = {};

    for (int ks = 0; ks < 12; ++ks) {
        const int k0 = ks * 32;
        // stage A: 128x32 fp32 -> bf16 LDS
#pragma unroll
        for (int i = 0; i < 4; ++i) {
            int c = tid + 256 * i;
            int row = c >> 3, q4 = c & 7;
            float4 f = *reinterpret_cast<const float4*>(x + (size_t)(row0 + row) * 384 + k0 + q4 * 4);
            ushort4 h;
            h.x = f2bf(f.x); h.y = f2bf(f.y); h.z = f2bf(f.z); h.w = f2bf(f.w);
            *reinterpret_cast<ushort4*>(&A_lds[row * 40 + q4 * 4]) = h;
        }
        // stage B: 192x32 bf16 (already transposed: Wt[col][k])
#pragma unroll
        for (int i = 0; i < 3; ++i) {
            int c = tid + 256 * i;
            int col = c >> 2, q8 = c & 3;
            bf16x8 wv = *reinterpret_cast<const bf16x8*>(Wt + (size_t)col * 384 + k0 + q8 * 8);
            *reinterpret_cast<bf16x8*>(&B_lds[col * 40 + q8 * 8]) = wv;
        }
        __syncthreads();

        bf16x8 a[4], b[6];
#pragma unroll
        for (int m = 0; m < 4; ++m)
            a[m] = *reinterpret_cast<const bf16x8*>(&A_lds[(wr * 64 + m * 16 + l15) * 40 + lg * 8]);
#pragma unroll
        for (int n = 0; n < 6; ++n)
            b[n] = *reinterpret_cast<const bf16x8*>(&B_lds[(wc * 96 + n * 16 + l15) * 40 + lg * 8]);
#pragma unroll
        for (int m = 0; m < 4; ++m)
#pragma unroll
            for (int n = 0; n < 6; ++n)
                acc[m][n] = __builtin_amdgcn_mfma_f32_16x16x32_bf16(a[m], b[n], acc[m][n], 0, 0, 0);
        __syncthreads();
    }

    // epilogue: C/D layout col=lane&15, row=(lane>>4)*4+j
#pragma unroll
    for (int m = 0; m < 4; ++m) {
#pragma unroll
        for (int n = 0; n < 6; ++n) {
            int colb = wc * 96 + n * 16 + l15;
#pragma unroll
            for (int j = 0; j < 4; ++j) {
                int row = row0 + wr * 64 + m * 16 + lg * 4 + j;
                unsigned short hv = f2bf(acc[m][n][j]);
                if (colb < 64) {
                    q_ws[(size_t)row * 64 + colb] = hv;
                } else if (colb < 128) {
                    k_ws[(size_t)row * 64 + (colb - 64)] = hv;
                } else {
                    int bb = row >> 8, t = row & 255, h = colb - 128;
                    vt_ws[((size_t)bb * 64 + h) * 256 + t] = hv;   // v stored transposed
                }
            }
        }
    }
}

// ---------------- kernel 2: causal flash attention, one block per batch ----------------
__global__ __launch_bounds__(256, 1) void attn(const unsigned short* __restrict__ q_ws,
                                               const unsigned short* __restrict__ k_ws,
                                               const unsigned short* __restrict__ vt_ws,
                                               float* __restrict__ out) {
    __shared__ unsigned short P_lds[4][64][72];   // per-wave P staging, padded

    const int b = blockIdx.x;
    const int tid = threadIdx.x, lane = tid & 63, w = tid >> 6;
    const int l15 = lane & 15, lg = lane >> 4;
    const unsigned short* qb = q_ws + (size_t)b * 256 * 64;
    const unsigned short* kb = k_ws + (size_t)b * 256 * 64;
    const unsigned short* vb = vt_ws + (size_t)b * 64 * 256;
    float* ob = out + (size_t)b * 256 * 64;
    const int r0 = w * 64;
    const float scale = 0.05103103630798287f;     // 384^-0.5

    f32x4 o[4][4] = {};
    float M[4][4], L[4][4];
#pragma unroll
    for (int m = 0; m < 4; ++m)
#pragma unroll
        for (int j = 0; j < 4; ++j) { M[m][j] = -1e30f; L[m][j] = 0.f; }

    for (int jt = 0; jt <= w; ++jt) {
        // ---- S = q @ K^T for this 64-col tile ----
        f32x4 s[4][4] = {};
#pragma unroll
        for (int kk = 0; kk < 2; ++kk) {
            bf16x8 aq[4], bk[4];
#pragma unroll
            for (int m = 0; m < 4; ++m)
                aq[m] = *reinterpret_cast<const bf16x8*>(qb + (size_t)(r0 + m * 16 + l15) * 64 + kk * 32 + lg * 8);
#pragma unroll
            for (int n = 0; n < 4; ++n)
                bk[n] = *reinterpret_cast<const bf16x8*>(kb + (size_t)(jt * 64 + n * 16 + l15) * 64 + kk * 32 + lg * 8);
#pragma unroll
            for (int m = 0; m < 4; ++m)
#pragma unroll
                for (int n = 0; n < 4; ++n)
                    s[m][n] = __builtin_amdgcn_mfma_f32_16x16x32_bf16(aq[m], bk[n], s[m][n], 0, 0, 0);
        }
        // ---- scale + causal mask + tile row-max ----
        float tm[4][4];
#pragma unroll
        for (int m = 0; m < 4; ++m)
#pragma unroll
            for (int j = 0; j < 4; ++j) tm[m][j] = -1e30f;
#pragma unroll
        for (int m = 0; m < 4; ++m) {
#pragma unroll
            for (int n = 0; n < 4; ++n) {
                int colg = jt * 64 + n * 16 + l15;
#pragma unroll
                for (int j = 0; j < 4; ++j) {
                    int rowg = r0 + m * 16 + lg * 4 + j;
                    float v = s[m][n][j] * scale;
                    if (colg > rowg) v = -1e30f;
                    s[m][n][j] = v;
                    tm[m][j] = fmaxf(tm[m][j], v);
                }
            }
        }
#pragma unroll
        for (int m = 0; m < 4; ++m)
#pragma unroll
            for (int j = 0; j < 4; ++j) {
                float v = tm[m][j];
                v = fmaxf(v, __shfl_xor(v, 1));
                v = fmaxf(v, __shfl_xor(v, 2));
                v = fmaxf(v, __shfl_xor(v, 4));
                v = fmaxf(v, __shfl_xor(v, 8));
                tm[m][j] = v;
            }
        float alpha[4][4];
#pragma unroll
        for (int m = 0; m < 4; ++m)
#pragma unroll
            for (int j = 0; j < 4; ++j) {
                float mn = fmaxf(M[m][j], tm[m][j]);
                alpha[m][j] = __expf(M[m][j] - mn);
                M[m][j] = mn;
            }
        // ---- P = exp(S - M), tile row-sum ----
        float ts[4][4] = {};
#pragma unroll
        for (int m = 0; m < 4; ++m)
#pragma unroll
            for (int n = 0; n < 4; ++n)
#pragma unroll
                for (int j = 0; j < 4; ++j) {
                    float p = __expf(s[m][n][j] - M[m][j]);
                    s[m][n][j] = p;
                    ts[m][j] += p;
                }
#pragma unroll
        for (int m = 0; m < 4; ++m)
#pragma unroll
            for (int j = 0; j < 4; ++j) {
                float v = ts[m][j];
                v += __shfl_xor(v, 1);
                v += __shfl_xor(v, 2);
                v += __shfl_xor(v, 4);
                v += __shfl_xor(v, 8);
                L[m][j] = L[m][j] * alpha[m][j] + v;
            }
        // ---- rescale O ----
#pragma unroll
        for (int m = 0; m < 4; ++m)
#pragma unroll
            for (int n = 0; n < 4; ++n)
#pragma unroll
                for (int j = 0; j < 4; ++j) o[m][n][j] *= alpha[m][j];
        // ---- P -> LDS (bf16) for A-operand restage ----
#pragma unroll
        for (int m = 0; m < 4; ++m)
#pragma unroll
            for (int n = 0; n < 4; ++n)
#pragma unroll
                for (int j = 0; j < 4; ++j)
                    P_lds[w][m * 16 + lg * 4 + j][n * 16 + l15] = f2bf(s[m][n][j]);
        asm volatile("s_waitcnt lgkmcnt(0)" ::: "memory");   // wave-internal LDS RAW fence
        // ---- O += P @ V  (V transposed in global: vb[h][t]) ----
#pragma unroll
        for (int kk = 0; kk < 2; ++kk) {
            bf16x8 ap[4], bv[4];
#pragma unroll
            for (int m = 0; m < 4; ++m)
                ap[m] = *reinterpret_cast<const bf16x8*>(&P_lds[w][m * 16 + l15][kk * 32 + lg * 8]);
#pragma unroll
            for (int n = 0; n < 4; ++n)
                bv[n] = *reinterpret_cast<const bf16x8*>(vb + (size_t)(n * 16 + l15) * 256 + jt * 64 + kk * 32 + lg * 8);
#pragma unroll
            for (int m = 0; m < 4; ++m)
#pragma unroll
                for (int n = 0; n < 4; ++n)
                    o[m][n] = __builtin_amdgcn_mfma_f32_16x16x32_bf16(ap[m], bv[n], o[m][n], 0, 0, 0);
        }
    }
    // ---- normalize + store fp32 ----
#pragma unroll
    for (int m = 0; m < 4; ++m) {
#pragma unroll
        for (int n = 0; n < 4; ++n) {
            int h = n * 16 + l15;
#pragma unroll
            for (int j = 0; j < 4; ++j) {
                int t = r0 + m * 16 + lg * 4 + j;
                ob[(size_t)t * 64 + h] = o[m][n][j] / L[m][j];
            }
        }
    }
}

extern "C" void kernel_launch(void* const* d_in, const int* in_sizes, int n_in,
                              void* d_out, int out_size, void* d_ws, size_t ws_size,
                              hipStream_t stream) {
    const float* x  = (const float*)d_in[0];
    const float* Wq = (const float*)d_in[1];
    const float* Wk = (const float*)d_in[2];
    const float* Wv = (const float*)d_in[3];
    float* out = (float*)d_out;

    char* ws = (char*)d_ws;
    unsigned short* q_ws  = (unsigned short*)(ws);                 // [65536][64] bf16
    unsigned short* k_ws  = (unsigned short*)(ws + 8388608);       // [65536][64] bf16
    unsigned short* vt_ws = (unsigned short*)(ws + 16777216);      // [256][64][256] bf16 (v^T)
    unsigned short* Wt    = (unsigned short*)(ws + 25165824);      // [192][384] bf16

    wprep<<<288, 256, 0, stream>>>(Wq, Wk, Wv, Wt);
    qkv_gemm<<<512, 256, 0, stream>>>(x, Wt, q_ws, k_ws, vt_ws);
    attn<<<256, 256, 0, stream>>>(q_ws, k_ws, vt_ws, out);
}

// Round 2
// 62.412 us; speedup vs baseline: 1.2035x; 1.2035x over previous
//
#include <hip/hip_runtime.h>
#include <hip/hip_bf16.h>

typedef __attribute__((ext_vector_type(8))) short bf16x8;
typedef __attribute__((ext_vector_type(4))) float f32x4;

__device__ __forceinline__ unsigned short f2bf(float f) {
    union { float f; unsigned int u; } v; v.f = f;
    unsigned int u = v.u;
    unsigned int r = u + 0x7FFFu + ((u >> 16) & 1u);   // RNE
    return (unsigned short)(r >> 16);
}

// ---------------- kernel 0: W transpose+convert -> Wt[192][384] bf16 ----------------
__global__ __launch_bounds__(256) void wprep(const float* __restrict__ Wq,
                                             const float* __restrict__ Wk,
                                             const float* __restrict__ Wv,
                                             unsigned short* __restrict__ Wt) {
    int idx = blockIdx.x * 256 + threadIdx.x;          // 3*64*384 = 73728
    if (idx >= 3 * 64 * 384) return;
    int w   = idx / (64 * 384);
    int rem = idx % (64 * 384);
    int n = rem / 384, k = rem % 384;
    const float* W = (w == 0) ? Wq : ((w == 1) ? Wk : Wv);
    Wt[idx] = f2bf(W[k * 64 + n]);
}

// ---------------- kernel 1: qkv = x @ [Wq|Wk|Wv], bf16 MFMA ----------------
// M=65536, K=384, N=192. Block tile 256x192, 8 waves (4x2), wave tile 64x96.
// K-step 64 (6 iters). Single LDS buffer + register prefetch of next A-tile:
// the prefetch loads are REGISTER loads, so __syncthreads does not drain them
// (vmcnt only waited at the consuming ds_write next iteration) -> HBM latency
// hides under the MFMA phase.
__global__ __launch_bounds__(512, 2) void qkv_gemm(const float* __restrict__ x,
                                                   const unsigned short* __restrict__ Wt,
                                                   unsigned short* __restrict__ q_ws,
                                                   unsigned short* __restrict__ k_ws,
                                                   unsigned short* __restrict__ vt_ws) {
    __shared__ unsigned short A_lds[256 * 72];   // 256 rows x 64 k, stride 72 (144B, 16B-aligned, banks balanced)
    __shared__ unsigned short B_lds[192 * 72];   // 192 cols x 64 k

    const int tid  = threadIdx.x;
    const int lane = tid & 63;
    const int wid  = tid >> 6;
    const int wr = wid >> 1, wc = wid & 1;       // 4 x 2 wave grid
    const int row0 = blockIdx.x * 256;
    const int l15 = lane & 15, lg = lane >> 4;
    const float* xb = x + (size_t)row0 * 384;

    f32x4 acc[4][6] = {};

    // prologue: prefetch A step 0 (256x64 fp32 -> 8 float4 / thread, coalesced)
    float4 aR[8];
#pragma unroll
    for (int i = 0; i < 8; ++i) {
        int c = tid + 512 * i;                   // [0,4096): float4 id
        int row = c >> 4, f4 = c & 15;
        aR[i] = *reinterpret_cast<const float4*>(xb + (size_t)row * 384 + f4 * 4);
    }

    for (int s = 0; s < 6; ++s) {
        const int k0 = s * 64;
        if (s) __syncthreads();                  // all waves done reading LDS of step s-1

        // issue B loads for this step (Wt is L2-hot; latency covered by A convert below)
        bf16x8 bR[3];
#pragma unroll
        for (int i = 0; i < 3; ++i) {
            int c = tid + 512 * i;               // [0,1536): 16B chunk id
            int col = c >> 3, ch = c & 7;
            bR[i] = *reinterpret_cast<const bf16x8*>(Wt + (size_t)col * 384 + k0 + ch * 8);
        }
        // convert + write A (consumes aR loaded last iteration / prologue)
#pragma unroll
        for (int i = 0; i < 8; ++i) {
            int c = tid + 512 * i;
            int row = c >> 4, f4 = c & 15;
            ushort4 h;
            h.x = f2bf(aR[i].x); h.y = f2bf(aR[i].y); h.z = f2bf(aR[i].z); h.w = f2bf(aR[i].w);
            *reinterpret_cast<ushort4*>(&A_lds[row * 72 + f4 * 4]) = h;
        }
        // write B
#pragma unroll
        for (int i = 0; i < 3; ++i) {
            int c = tid + 512 * i;
            int col = c >> 3, ch = c & 7;
            *reinterpret_cast<bf16x8*>(&B_lds[col * 72 + ch * 8]) = bR[i];
        }
        // prefetch A for next step (in flight across the barrier, lands during MFMA)
        if (s < 5) {
#pragma unroll
            for (int i = 0; i < 8; ++i) {
                int c = tid + 512 * i;
                int row = c >> 4, f4 = c & 15;
                aR[i] = *reinterpret_cast<const float4*>(xb + (size_t)row * 384 + (k0 + 64) + f4 * 4);
            }
        }
        __syncthreads();

        // fragments + MFMA (48 per wave per step)
#pragma unroll
        for (int kk = 0; kk < 2; ++kk) {
            bf16x8 a[4], b[6];
#pragma unroll
            for (int m = 0; m < 4; ++m)
                a[m] = *reinterpret_cast<const bf16x8*>(&A_lds[(wr * 64 + m * 16 + l15) * 72 + kk * 32 + lg * 8]);
#pragma unroll
            for (int n = 0; n < 6; ++n)
                b[n] = *reinterpret_cast<const bf16x8*>(&B_lds[(wc * 96 + n * 16 + l15) * 72 + kk * 32 + lg * 8]);
#pragma unroll
            for (int m = 0; m < 4; ++m)
#pragma unroll
                for (int n = 0; n < 6; ++n)
                    acc[m][n] = __builtin_amdgcn_mfma_f32_16x16x32_bf16(a[m], b[n], acc[m][n], 0, 0, 0);
        }
    }

    // epilogue: C/D layout col=lane&15, row=(lane>>4)*4+j
#pragma unroll
    for (int m = 0; m < 4; ++m) {
#pragma unroll
        for (int n = 0; n < 6; ++n) {
            int colb = wc * 96 + n * 16 + l15;
#pragma unroll
            for (int j = 0; j < 4; ++j) {
                int row = row0 + wr * 64 + m * 16 + lg * 4 + j;
                unsigned short hv = f2bf(acc[m][n][j]);
                if (colb < 64) {
                    q_ws[(size_t)row * 64 + colb] = hv;
                } else if (colb < 128) {
                    k_ws[(size_t)row * 64 + (colb - 64)] = hv;
                } else {
                    int bb = row >> 8, t = row & 255, h = colb - 128;
                    vt_ws[((size_t)bb * 64 + h) * 256 + t] = hv;   // v stored transposed
                }
            }
        }
    }
}

// ---------------- kernel 2: causal flash attention, one block per batch ----------------
__global__ __launch_bounds__(256, 1) void attn(const unsigned short* __restrict__ q_ws,
                                               const unsigned short* __restrict__ k_ws,
                                               const unsigned short* __restrict__ vt_ws,
                                               float* __restrict__ out) {
    __shared__ unsigned short P_lds[4][64][72];   // per-wave P staging, padded

    const int b = blockIdx.x;
    const int tid = threadIdx.x, lane = tid & 63, w = tid >> 6;
    const int l15 = lane & 15, lg = lane >> 4;
    const unsigned short* qb = q_ws + (size_t)b * 256 * 64;
    const unsigned short* kb = k_ws + (size_t)b * 256 * 64;
    const unsigned short* vb = vt_ws + (size_t)b * 64 * 256;
    float* ob = out + (size_t)b * 256 * 64;
    const int r0 = w * 64;
    const float scale = 0.05103103630798287f;     // 384^-0.5

    f32x4 o[4][4] = {};
    float M[4][4], L[4][4];
#pragma unroll
    for (int m = 0; m < 4; ++m)
#pragma unroll
        for (int j = 0; j < 4; ++j) { M[m][j] = -1e30f; L[m][j] = 0.f; }

    for (int jt = 0; jt <= w; ++jt) {
        // ---- S = q @ K^T for this 64-col tile ----
        f32x4 s[4][4] = {};
#pragma unroll
        for (int kk = 0; kk < 2; ++kk) {
            bf16x8 aq[4], bk[4];
#pragma unroll
            for (int m = 0; m < 4; ++m)
                aq[m] = *reinterpret_cast<const bf16x8*>(qb + (size_t)(r0 + m * 16 + l15) * 64 + kk * 32 + lg * 8);
#pragma unroll
            for (int n = 0; n < 4; ++n)
                bk[n] = *reinterpret_cast<const bf16x8*>(kb + (size_t)(jt * 64 + n * 16 + l15) * 64 + kk * 32 + lg * 8);
#pragma unroll
            for (int m = 0; m < 4; ++m)
#pragma unroll
                for (int n = 0; n < 4; ++n)
                    s[m][n] = __builtin_amdgcn_mfma_f32_16x16x32_bf16(aq[m], bk[n], s[m][n], 0, 0, 0);
        }
        // ---- scale + causal mask + tile row-max ----
        float tm[4][4];
#pragma unroll
        for (int m = 0; m < 4; ++m)
#pragma unroll
            for (int j = 0; j < 4; ++j) tm[m][j] = -1e30f;
#pragma unroll
        for (int m = 0; m < 4; ++m) {
#pragma unroll
            for (int n = 0; n < 4; ++n) {
                int colg = jt * 64 + n * 16 + l15;
#pragma unroll
                for (int j = 0; j < 4; ++j) {
                    int rowg = r0 + m * 16 + lg * 4 + j;
                    float v = s[m][n][j] * scale;
                    if (colg > rowg) v = -1e30f;
                    s[m][n][j] = v;
                    tm[m][j] = fmaxf(tm[m][j], v);
                }
            }
        }
#pragma unroll
        for (int m = 0; m < 4; ++m)
#pragma unroll
            for (int j = 0; j < 4; ++j) {
                float v = tm[m][j];
                v = fmaxf(v, __shfl_xor(v, 1));
                v = fmaxf(v, __shfl_xor(v, 2));
                v = fmaxf(v, __shfl_xor(v, 4));
                v = fmaxf(v, __shfl_xor(v, 8));
                tm[m][j] = v;
            }
        float alpha[4][4];
#pragma unroll
        for (int m = 0; m < 4; ++m)
#pragma unroll
            for (int j = 0; j < 4; ++j) {
                float mn = fmaxf(M[m][j], tm[m][j]);
                alpha[m][j] = __expf(M[m][j] - mn);
                M[m][j] = mn;
            }
        // ---- P = exp(S - M), tile row-sum ----
        float ts[4][4] = {};
#pragma unroll
        for (int m = 0; m < 4; ++m)
#pragma unroll
            for (int n = 0; n < 4; ++n)
#pragma unroll
                for (int j = 0; j < 4; ++j) {
                    float p = __expf(s[m][n][j] - M[m][j]);
                    s[m][n][j] = p;
                    ts[m][j] += p;
                }
#pragma unroll
        for (int m = 0; m < 4; ++m)
#pragma unroll
            for (int j = 0; j < 4; ++j) {
                float v = ts[m][j];
                v += __shfl_xor(v, 1);
                v += __shfl_xor(v, 2);
                v += __shfl_xor(v, 4);
                v += __shfl_xor(v, 8);
                L[m][j] = L[m][j] * alpha[m][j] + v;
            }
        // ---- rescale O ----
#pragma unroll
        for (int m = 0; m < 4; ++m)
#pragma unroll
            for (int n = 0; n < 4; ++n)
#pragma unroll
                for (int j = 0; j < 4; ++j) o[m][n][j] *= alpha[m][j];
        // ---- P -> LDS (bf16) for A-operand restage ----
#pragma unroll
        for (int m = 0; m < 4; ++m)
#pragma unroll
            for (int n = 0; n < 4; ++n)
#pragma unroll
                for (int j = 0; j < 4; ++j)
                    P_lds[w][m * 16 + lg * 4 + j][n * 16 + l15] = f2bf(s[m][n][j]);
        asm volatile("s_waitcnt lgkmcnt(0)" ::: "memory");   // wave-internal LDS RAW fence
        // ---- O += P @ V  (V transposed in global: vb[h][t]) ----
#pragma unroll
        for (int kk = 0; kk < 2; ++kk) {
            bf16x8 ap[4], bv[4];
#pragma unroll
            for (int m = 0; m < 4; ++m)
                ap[m] = *reinterpret_cast<const bf16x8*>(&P_lds[w][m * 16 + l15][kk * 32 + lg * 8]);
#pragma unroll
            for (int n = 0; n < 4; ++n)
                bv[n] = *reinterpret_cast<const bf16x8*>(vb + (size_t)(n * 16 + l15) * 256 + jt * 64 + kk * 32 + lg * 8);
#pragma unroll
            for (int m = 0; m < 4; ++m)
#pragma unroll
                for (int n = 0; n < 4; ++n)
                    o[m][n] = __builtin_amdgcn_mfma_f32_16x16x32_bf16(ap[m], bv[n], o[m][n], 0, 0, 0);
        }
    }
    // ---- normalize + store fp32 ----
#pragma unroll
    for (int m = 0; m < 4; ++m) {
#pragma unroll
        for (int n = 0; n < 4; ++n) {
            int h = n * 16 + l15;
#pragma unroll
            for (int j = 0; j < 4; ++j) {
                int t = r0 + m * 16 + lg * 4 + j;
                ob[(size_t)t * 64 + h] = o[m][n][j] / L[m][j];
            }
        }
    }
}

extern "C" void kernel_launch(void* const* d_in, const int* in_sizes, int n_in,
                              void* d_out, int out_size, void* d_ws, size_t ws_size,
                              hipStream_t stream) {
    const float* x  = (const float*)d_in[0];
    const float* Wq = (const float*)d_in[1];
    const float* Wk = (const float*)d_in[2];
    const float* Wv = (const float*)d_in[3];
    float* out = (float*)d_out;

    char* ws = (char*)d_ws;
    unsigned short* q_ws  = (unsigned short*)(ws);                 // [65536][64] bf16
    unsigned short* k_ws  = (unsigned short*)(ws + 8388608);       // [65536][64] bf16
    unsigned short* vt_ws = (unsigned short*)(ws + 16777216);      // [256][64][256] bf16 (v^T)
    unsigned short* Wt    = (unsigned short*)(ws + 25165824);      // [192][384] bf16

    wprep<<<288, 256, 0, stream>>>(Wq, Wk, Wv, Wt);
    qkv_gemm<<<256, 512, 0, stream>>>(x, Wt, q_ws, k_ws, vt_ws);
    attn<<<256, 256, 0, stream>>>(q_ws, k_ws, vt_ws, out);
}